// Round 13
// baseline (232.330 us; speedup 1.0000x reference)
//
#include <hip/hip_runtime.h>

#define DIM 512
#define NTOK 2304
#define HEADS 8
#define HD 64
#define LN_EPS 1e-5f
#define BNC 2359296   // B*N*C = 2*2304*512
#define QSC 0.18033688011112042f   // 0.125 * log2(e): softmax in exp2 domain

typedef __attribute__((ext_vector_type(8))) short short8;
typedef __attribute__((ext_vector_type(4))) short sh4;
typedef __attribute__((ext_vector_type(4))) float f32x4;

__device__ __forceinline__ short f2bf(float f) {
    union { float f; unsigned u; } x; x.f = f;
    unsigned r = (x.u + 0x7fffu + ((x.u >> 16) & 1u)) >> 16;
    return (short)(r & 0xffffu);
}
__device__ __forceinline__ unsigned fbits(float f) {
    union { float f; unsigned u; } x; x.f = f; return x.u;
}
// async global->LDS DMA, 16B/lane; lds dest = wave-uniform base + lane*16
__device__ __forceinline__ void gl2lds(const short* g, short* l) {
    __builtin_amdgcn_global_load_lds(
        (const __attribute__((address_space(1))) unsigned int*)g,
        (__attribute__((address_space(3))) unsigned int*)l, 16, 0, 0);
}

// -------- fused prep: LN stats (blocks 0..143, 4-way c-split) + weight transpose (144..335) --------
__global__ void k_prep(const float* __restrict__ x, const float* __restrict__ y,
                       float* __restrict__ mu, float* __restrict__ rs,
                       const float* __restrict__ qv_w, const float* __restrict__ k_w,
                       const float* __restrict__ qv_b, const float* __restrict__ k_b,
                       short* __restrict__ Wt, float* __restrict__ bias) {
    __shared__ __align__(16) float tile[64][65];
    __shared__ float pS[4][64], pQ[4][64];
    int bx = blockIdx.x, tid = threadIdx.x;
    if (bx < 144) {
        int nt = bx % 36, sb = bx / 36;
        int nl = tid & 63, part = tid >> 6;
        int n = nt * 64 + nl;
        int s = sb >> 1, b = sb & 1;
        const float* src = (s ? y : x) + (size_t)b * DIM * NTOK + n;
        float sum = 0.f, sq = 0.f;
        for (int c = part * 128; c < part * 128 + 128; c++) {
            float v = src[(size_t)c * NTOK];
            sum += v; sq += v * v;
        }
        pS[part][nl] = sum; pQ[part][nl] = sq;
        __syncthreads();
        if (tid < 64) {
            float ts = pS[0][tid] + pS[1][tid] + pS[2][tid] + pS[3][tid];
            float tq = pQ[0][tid] + pQ[1][tid] + pQ[2][tid] + pQ[3][tid];
            float m = ts * (1.0f / DIM);
            float var = tq * (1.0f / DIM) - m * m;
            mu[sb * NTOK + nt * 64 + tid] = m;
            rs[sb * NTOK + nt * 64 + tid] = rsqrtf(var + LN_EPS);
        }
        return;
    }
    int idx = bx - 144;
    int jt = idx % 24, ct = idx / 24;
    int j0 = jt * 64, c0 = ct * 64;
    if (ct == 0 && tid < 64) {
        int j = j0 + tid;
        bias[j] = (j < 1024) ? qv_b[j] : k_b[j - 1024];
    }
    for (int slot = tid; slot < 1024; slot += 256) {
        int r = slot >> 4, q = slot & 15;
        int c = c0 + r;
        float4 v;
        if (j0 < 1024) v = *(const float4*)(qv_w + (size_t)c * 1024 + j0 + q * 4);
        else           v = *(const float4*)(k_w  + (size_t)c * 512  + (j0 - 1024) + q * 4);
        tile[r][q*4+0] = v.x; tile[r][q*4+1] = v.y;
        tile[r][q*4+2] = v.z; tile[r][q*4+3] = v.w;
    }
    __syncthreads();
    int jr = tid >> 2, cg = tid & 3;
    short8 o0, o1;
    for (int i = 0; i < 8; i++) o0[i] = f2bf(tile[cg*16+i][jr]);
    for (int i = 0; i < 8; i++) o1[i] = f2bf(tile[cg*16+8+i][jr]);
    short* dst = Wt + (size_t)(j0 + jr) * DIM + c0 + cg * 16;
    *(short8*)dst = o0;
    *(short8*)(dst + 8) = o1;
}

// ---------------- normalize + transpose -> T[s][b][n][c] bf16 ----------------
__global__ void k_normT(const float* __restrict__ x, const float* __restrict__ y,
                        const float* __restrict__ mu, const float* __restrict__ rs,
                        const float* __restrict__ gx, const float* __restrict__ bx,
                        const float* __restrict__ gy, const float* __restrict__ by,
                        short* __restrict__ T) {
    __shared__ __align__(16) float tile[64][65];
    int nt = blockIdx.x, ct = blockIdx.y, sb = blockIdx.z;
    int s = sb >> 1, b = sb & 1;
    int n0 = nt * 64, c0 = ct * 64;
    const float* src = (s ? y : x) + (size_t)b * DIM * NTOK;
    int tid = threadIdx.x;
    for (int slot = tid; slot < 1024; slot += 256) {
        int r = slot >> 4, q = slot & 15;
        const float* p = src + (size_t)(c0 + r) * NTOK + n0 + q * 4;
        float4 v = *(const float4*)p;
        tile[r][q*4+0] = v.x; tile[r][q*4+1] = v.y;
        tile[r][q*4+2] = v.z; tile[r][q*4+3] = v.w;
    }
    __syncthreads();
    const float* g  = s ? gy : gx;
    const float* be = s ? by : bx;
    int nr = tid >> 2, cg = tid & 3;
    int n = n0 + nr;
    float m = mu[sb * NTOK + n], r_ = rs[sb * NTOK + n];
    short8 o0, o1;
    for (int i = 0; i < 8; i++) {
        int c = c0 + cg * 16 + i;
        o0[i] = f2bf((tile[cg*16+i][nr] - m) * r_ * g[c] + be[c]);
    }
    for (int i = 0; i < 8; i++) {
        int c = c0 + cg * 16 + 8 + i;
        o1[i] = f2bf((tile[cg*16+8+i][nr] - m) * r_ * g[c] + be[c]);
    }
    short* dst = T + ((size_t)sb * NTOK + n) * DIM + c0 + cg * 16;
    *(short8*)dst = o0;
    *(short8*)(dst + 8) = o1;
}

// -------- GEMM: 128x128 tile, DMA staging + XOR swizzle, Q pre-scaled --------
// V-region blocks (j0 in [512,1024)) transpose their tile via LDS and write VT
// directly (coalesced row stores).
__global__ void __launch_bounds__(256)
k_gemm(const short* __restrict__ T, const short* __restrict__ Wt,
       const float* __restrict__ bias, short* __restrict__ QVK,
       short* __restrict__ VT) {
    __shared__ __align__(16) short smem[2 * 128 * 64];
    short* As = smem;
    short* Bs = smem + 128 * 64;
    int n0 = blockIdx.x * 128, j0 = blockIdx.y * 128, sb = blockIdx.z;
    int tid = threadIdx.x;
    int w = tid >> 6, l = tid & 63;
    int wr = w >> 1, wc = w & 1;
    int lrow = l & 15, quad = l >> 4;
    int r_in = (l >> 3) & 7, cc = l & 7;
    int ch = cc ^ r_in;                       // swizzled source chunk
    int sw0 = (quad ^ (lrow & 7)) * 8;        // frag-read chunk offset (shorts)
    const short* Ab = T + (size_t)sb * NTOK * DIM;
    f32x4 acc[4][4] = {};
    for (int kk = 0; kk < 8; kk++) {
        if (kk) __syncthreads();
        for (int inst = 0; inst < 4; inst++) {
            int R = w * 32 + inst * 8 + r_in;
            gl2lds(Ab + (size_t)(n0 + R) * 512 + kk * 64 + ch * 8,
                   &As[(w * 32 + inst * 8) * 64]);
            gl2lds(Wt + (size_t)(j0 + R) * 512 + kk * 64 + ch * 8,
                   &Bs[(w * 32 + inst * 8) * 64]);
        }
        __syncthreads();
        for (int c2 = 0; c2 < 2; c2++) {
            int off = c2 ? (sw0 ^ 32) : sw0;
            short8 af[4], bf[4];
            for (int i = 0; i < 4; i++)
                af[i] = *(const short8*)&As[(wr*64 + i*16 + lrow) * 64 + off];
            for (int j = 0; j < 4; j++)
                bf[j] = *(const short8*)&Bs[(wc*64 + j*16 + lrow) * 64 + off];
            for (int i = 0; i < 4; i++)
                for (int j = 0; j < 4; j++)
                    acc[i][j] = __builtin_amdgcn_mfma_f32_16x16x32_bf16(af[i], bf[j], acc[i][j], 0, 0, 0);
        }
    }
    if (j0 >= 512 && j0 < 1024) {
        // ---- V block: transpose tile in LDS (reuse As+Bs as 128x128), write VT ----
        __syncthreads();               // main-loop LDS readers done
        for (int i = 0; i < 4; i++)
            for (int j = 0; j < 4; j++) {
                int jloc = wc * 64 + j * 16 + lrow;           // V row (within tile)
                float bv = bias[j0 + jloc];
                int nloc = wr * 64 + i * 16 + quad * 4;       // n col
                int c8 = nloc >> 3, half = (nloc >> 2) & 1;
                sh4 pk;
                for (int reg = 0; reg < 4; reg++) pk[reg] = f2bf(acc[i][j][reg] + bv);
                *(sh4*)&smem[jloc * 128 + ((c8 ^ (jloc & 15)) * 8) + half * 4] = pk;
            }
        __syncthreads();
        for (int slot = tid; slot < 2048; slot += 256) {
            int row = slot >> 4, seg = slot & 15;
            short8 v = *(const short8*)&smem[row * 128 + ((seg ^ (row & 15)) * 8)];
            *(short8*)(VT + ((size_t)sb * 512 + (j0 - 512) + row) * NTOK + n0 + seg * 8) = v;
        }
    } else {
        for (int i = 0; i < 4; i++)
            for (int j = 0; j < 4; j++) {
                int jj = j0 + wc * 64 + j * 16 + lrow;
                float bv = bias[jj];
                float sc = (jj < 512) ? QSC : 1.0f;   // Q pre-scaled into exp2 domain
                for (int reg = 0; reg < 4; reg++) {
                    int n = n0 + wr * 64 + i * 16 + quad * 4 + reg;
                    QVK[((size_t)sb * NTOK + n) * 1536 + jj] = f2bf((acc[i][j][reg] + bv) * sc);
                }
            }
    }
}

// ---------------- flash attention: q-tile 32, 2-wave blocks, single-buffer DMA K/V ----------------
// Per-wave code identical to the proven R11 kernel (S^T scores, no-max exp2 softmax,
// ones-MFMA l-sum, O^T PV); block shrunk to 2 waves so the grid gives 2304 blocks
// (9/CU) and LDS 20 KB caps at 8 blocks/CU -> ~16 co-resident waves/CU (vs 11.5).
__global__ void __launch_bounds__(128)
k_attn(const short* __restrict__ QVK, const short* __restrict__ VT,
       float* __restrict__ out) {
    __shared__ __align__(16) short Ks[64 * 64];   // 8 KB
    __shared__ __align__(16) short Vs[64 * 64];   // 8 KB
    __shared__ __align__(16) short Qs[32 * 64];   // 4 KB; Q staging, re-used as P
    int qt = blockIdx.x;              // 0..71
    int yb = blockIdx.y;              // 0..31
    int br = yb >> 4;
    int b  = (yb >> 3) & 1;
    int h  = yb & 7;
    int tid = threadIdx.x;
    int w = tid >> 6, l = tid & 63;   // w in {0,1}
    int lrow = l & 15, quad = l >> 4;
    int r_in = (l >> 3) & 7, cc = l & 7;
    int ch = cc ^ r_in;
    int sw0 = (quad ^ (lrow & 7)) * 8;
    int n0 = qt * 32;
    const short* Qg = QVK + ((size_t)(br * 2 + b) * NTOK) * 1536 + h * 64;           // exp2-scaled Q
    const short* Kg = QVK + ((size_t)((1 - br) * 2 + b) * NTOK) * 1536 + 1024 + h * 64;
    const short* Vg = VT + ((size_t)(br * 2 + b) * 512 + h * 64) * NTOK;

    // stage Q (wave w: rows w*16..w*16+15)
    for (int inst = 0; inst < 2; inst++) {
        int R = w * 16 + inst * 8 + r_in;
        gl2lds(Qg + (size_t)(n0 + R) * 1536 + ch * 8, &Qs[(w * 16 + inst * 8) * 64]);
    }
    __syncthreads();
    short8 bq0 = *(const short8*)&Qs[(w * 16 + lrow) * 64 + sw0];
    short8 bq1 = *(const short8*)&Qs[(w * 16 + lrow) * 64 + (sw0 ^ 32)];
    short* Pw = &Qs[w * 16 * 64];     // wave-private P region (16 rows)

    short8 ones;
    for (int i = 0; i < 8; i++) ones[i] = (short)0x3F80;   // bf16 1.0

    f32x4 Oacc[4] = {};
    f32x4 lacc = {};

    for (int mt = 0; mt < 36; mt++) {
        int m0 = mt * 64;
        __syncthreads();              // prev-tile readers done (also covers Q->P reuse)
        for (int inst = 0; inst < 4; inst++) {
            int R = w * 32 + inst * 8 + r_in;
            int Rb = (w * 32 + inst * 8) * 64;
            gl2lds(Kg + (size_t)(m0 + R) * 1536 + ch * 8, &Ks[Rb]);
            gl2lds(Vg + (size_t)R * NTOK + m0 + ch * 8, &Vs[Rb]);
        }
        __syncthreads();              // drain DMA

        for (int sub = 0; sub < 4; sub++) {
            short8 ak0 = *(const short8*)&Ks[(sub * 16 + lrow) * 64 + sw0];
            short8 ak1 = *(const short8*)&Ks[(sub * 16 + lrow) * 64 + (sw0 ^ 32)];
            f32x4 a = {};
            a = __builtin_amdgcn_mfma_f32_16x16x32_bf16(ak0, bq0, a, 0, 0, 0);
            a = __builtin_amdgcn_mfma_f32_16x16x32_bf16(ak1, bq1, a, 0, 0, 0);
            float p0 = exp2f(a[0]), p1 = exp2f(a[1]);
            float p2 = exp2f(a[2]), p3 = exp2f(a[3]);
            uint2 pk;
            pk.x = __builtin_amdgcn_perm(fbits(p1), fbits(p0), 0x07060302u);
            pk.y = __builtin_amdgcn_perm(fbits(p3), fbits(p2), 0x07060302u);
            *(uint2*)&Pw[lrow * 64 + (((2 * sub + (quad >> 1)) ^ (lrow & 7)) * 8) + (quad & 1) * 4] = pk;
        }

        // PV + l-sum: same-wave LDS dep only, no barrier
        short8 ap0 = *(const short8*)&Pw[lrow * 64 + sw0];
        short8 ap1 = *(const short8*)&Pw[lrow * 64 + (sw0 ^ 32)];
        lacc = __builtin_amdgcn_mfma_f32_16x16x32_bf16(ones, ap0, lacc, 0, 0, 0);
        lacc = __builtin_amdgcn_mfma_f32_16x16x32_bf16(ones, ap1, lacc, 0, 0, 0);
        for (int ddt = 0; ddt < 4; ddt++) {
            short8 av0 = *(const short8*)&Vs[(ddt * 16 + lrow) * 64 + sw0];
            short8 av1 = *(const short8*)&Vs[(ddt * 16 + lrow) * 64 + (sw0 ^ 32)];
            Oacc[ddt] = __builtin_amdgcn_mfma_f32_16x16x32_bf16(av0, ap0, Oacc[ddt], 0, 0, 0);
            Oacc[ddt] = __builtin_amdgcn_mfma_f32_16x16x32_bf16(av1, ap1, Oacc[ddt], 0, 0, 0);
        }
    }

    float linv = 1.f / lacc[0];       // all rows of lacc identical (ones A-operand)
    int n = n0 + w * 16 + lrow;
    for (int ddt = 0; ddt < 4; ddt++) {
        float4 o;
        o.x = Oacc[ddt][0] * linv;
        o.y = Oacc[ddt][1] * linv;
        o.z = Oacc[ddt][2] * linv;
        o.w = Oacc[ddt][3] * linv;
        if (br == 0)
            *(float4*)&out[((size_t)b * NTOK + n) * 512 + h * 64 + ddt * 16 + quad * 4] = o;
        else
            *(float4*)&out[(size_t)BNC + ((size_t)(h * 2 + b) * NTOK + n) * 64 + ddt * 16 + quad * 4] = o;
    }
}

extern "C" void kernel_launch(void* const* d_in, const int* in_sizes, int n_in,
                              void* d_out, int out_size, void* d_ws, size_t ws_size,
                              hipStream_t stream) {
    const float* x     = (const float*)d_in[0];
    const float* y     = (const float*)d_in[1];
    const float* k_w   = (const float*)d_in[2];
    const float* k_b   = (const float*)d_in[3];
    const float* qv_w  = (const float*)d_in[4];
    const float* qv_b  = (const float*)d_in[5];
    const float* lnx_g = (const float*)d_in[6];
    const float* lnx_b = (const float*)d_in[7];
    const float* lny_g = (const float*)d_in[8];
    const float* lny_b = (const float*)d_in[9];
    float* out = (float*)d_out;

    char* ws = (char*)d_ws;
    float* mu   = (float*)ws;                 // 9216 f32
    float* rs   = mu + 9216;                  // 9216 f32
    float* bias = rs + 9216;                  // 1536 f32  (ends at 79872 B)
    short* T    = (short*)(ws + 79872);       // 4,718,592 bf16
    short* Wt   = T + 4718592;                // 786,432 bf16
    short* QVK  = Wt + 786432;                // 14,155,776 bf16 (V region unused)
    short* VT   = QVK + 14155776;             // 4,718,592 bf16

    k_prep  <<<336, 256, 0, stream>>>(x, y, mu, rs, qv_w, k_w, qv_b, k_b, Wt, bias);
    k_normT <<<dim3(36, 8, 4), 256, 0, stream>>>(x, y, mu, rs,
                                                 lnx_g, lnx_b, lny_g, lny_b, T);
    k_gemm  <<<dim3(18, 12, 4), 256, 0, stream>>>(T, Wt, bias, QVK, VT);
    k_attn  <<<dim3(72, 32), 128, 0, stream>>>(QVK, VT, out);
}

// Round 14
// 202.636 us; speedup vs baseline: 1.1465x; 1.1465x over previous
//
#include <hip/hip_runtime.h>

#define DIM 512
#define NTOK 2304
#define HEADS 8
#define HD 64
#define LN_EPS 1e-5f
#define BNC 2359296   // B*N*C = 2*2304*512
#define QSC 0.18033688011112042f   // 0.125 * log2(e): softmax in exp2 domain

typedef __attribute__((ext_vector_type(8))) short short8;
typedef __attribute__((ext_vector_type(4))) short sh4;
typedef __attribute__((ext_vector_type(4))) float f32x4;

__device__ __forceinline__ short f2bf(float f) {
    union { float f; unsigned u; } x; x.f = f;
    unsigned r = (x.u + 0x7fffu + ((x.u >> 16) & 1u)) >> 16;
    return (short)(r & 0xffffu);
}
__device__ __forceinline__ unsigned fbits(float f) {
    union { float f; unsigned u; } x; x.f = f; return x.u;
}
// async global->LDS DMA, 16B/lane; lds dest = wave-uniform base + lane*16
__device__ __forceinline__ void gl2lds(const short* g, short* l) {
    __builtin_amdgcn_global_load_lds(
        (const __attribute__((address_space(1))) unsigned int*)g,
        (__attribute__((address_space(3))) unsigned int*)l, 16, 0, 0);
}

// -------- fused pre: stats+normalize+transpose (blocks 0..1151) + weight transpose (1152..1343) --------
// normT blocks recompute their 64 tokens' LN stats from L2 (8x redundant reads,
// ~4 us aggregate) -- removes the separate stats pass and the mu/rs round-trip.
__global__ void k_pre(const float* __restrict__ x, const float* __restrict__ y,
                      const float* __restrict__ qv_w, const float* __restrict__ k_w,
                      const float* __restrict__ qv_b, const float* __restrict__ k_b,
                      const float* __restrict__ gx, const float* __restrict__ bx,
                      const float* __restrict__ gy, const float* __restrict__ by,
                      short* __restrict__ T, short* __restrict__ Wt,
                      float* __restrict__ bias) {
    __shared__ __align__(16) float tile[64][65];
    __shared__ float pS[4][64], pQ[4][64];
    __shared__ float muL[64], rsL[64];
    int bkid = blockIdx.x, tid = threadIdx.x;
    if (bkid < 1152) {
        int nt = bkid % 36, ct = (bkid / 36) % 8, sb = bkid / 288;
        int s = sb >> 1, b = sb & 1;
        int n0 = nt * 64, c0 = ct * 64;
        const float* src = (s ? y : x) + (size_t)b * DIM * NTOK;
        // phase 1: LN stats for tokens n0..n0+63 (full 512-c read, 4-way split)
        int nl = tid & 63, part = tid >> 6;
        {
            const float* p = src + n0 + nl;
            float sum = 0.f, sq = 0.f;
            for (int c = part * 128; c < part * 128 + 128; c++) {
                float v = p[(size_t)c * NTOK];
                sum += v; sq += v * v;
            }
            pS[part][nl] = sum; pQ[part][nl] = sq;
        }
        __syncthreads();
        if (tid < 64) {
            float ts = pS[0][tid] + pS[1][tid] + pS[2][tid] + pS[3][tid];
            float tq = pQ[0][tid] + pQ[1][tid] + pQ[2][tid] + pQ[3][tid];
            float m = ts * (1.0f / DIM);
            float var = tq * (1.0f / DIM) - m * m;
            muL[tid] = m;
            rsL[tid] = rsqrtf(var + LN_EPS);
        }
        // phase 2: load c-tile, normalize, transpose-store
        for (int slot = tid; slot < 1024; slot += 256) {
            int r = slot >> 4, q = slot & 15;
            const float* p = src + (size_t)(c0 + r) * NTOK + n0 + q * 4;
            float4 v = *(const float4*)p;
            tile[r][q*4+0] = v.x; tile[r][q*4+1] = v.y;
            tile[r][q*4+2] = v.z; tile[r][q*4+3] = v.w;
        }
        __syncthreads();   // covers muL/rsL and tile
        const float* g  = s ? gy : gx;
        const float* be = s ? by : bx;
        int nr = tid >> 2, cg = tid & 3;
        float m = muL[nr], r_ = rsL[nr];
        short8 o0, o1;
        for (int i = 0; i < 8; i++) {
            int c = c0 + cg * 16 + i;
            o0[i] = f2bf((tile[cg*16+i][nr] - m) * r_ * g[c] + be[c]);
        }
        for (int i = 0; i < 8; i++) {
            int c = c0 + cg * 16 + 8 + i;
            o1[i] = f2bf((tile[cg*16+8+i][nr] - m) * r_ * g[c] + be[c]);
        }
        short* dst = T + ((size_t)sb * NTOK + n0 + nr) * DIM + c0 + cg * 16;
        *(short8*)dst = o0;
        *(short8*)(dst + 8) = o1;
        return;
    }
    // ---- weight transpose blocks ----
    int idx = bkid - 1152;
    int jt = idx % 24, ct = idx / 24;
    int j0 = jt * 64, c0 = ct * 64;
    if (ct == 0 && tid < 64) {
        int j = j0 + tid;
        bias[j] = (j < 1024) ? qv_b[j] : k_b[j - 1024];
    }
    for (int slot = tid; slot < 1024; slot += 256) {
        int r = slot >> 4, q = slot & 15;
        int c = c0 + r;
        float4 v;
        if (j0 < 1024) v = *(const float4*)(qv_w + (size_t)c * 1024 + j0 + q * 4);
        else           v = *(const float4*)(k_w  + (size_t)c * 512  + (j0 - 1024) + q * 4);
        tile[r][q*4+0] = v.x; tile[r][q*4+1] = v.y;
        tile[r][q*4+2] = v.z; tile[r][q*4+3] = v.w;
    }
    __syncthreads();
    int jr = tid >> 2, cg = tid & 3;
    short8 o0, o1;
    for (int i = 0; i < 8; i++) o0[i] = f2bf(tile[cg*16+i][jr]);
    for (int i = 0; i < 8; i++) o1[i] = f2bf(tile[cg*16+8+i][jr]);
    short* dst = Wt + (size_t)(j0 + jr) * DIM + c0 + cg * 16;
    *(short8*)dst = o0;
    *(short8*)(dst + 8) = o1;
}

// -------- GEMM: 128x128 tile, DMA staging + XOR swizzle, Q pre-scaled --------
// V-region blocks (j0 in [512,1024)) transpose their tile via LDS and write VT
// directly (coalesced row stores).
__global__ void __launch_bounds__(256)
k_gemm(const short* __restrict__ T, const short* __restrict__ Wt,
       const float* __restrict__ bias, short* __restrict__ QVK,
       short* __restrict__ VT) {
    __shared__ __align__(16) short smem[2 * 128 * 64];
    short* As = smem;
    short* Bs = smem + 128 * 64;
    int n0 = blockIdx.x * 128, j0 = blockIdx.y * 128, sb = blockIdx.z;
    int tid = threadIdx.x;
    int w = tid >> 6, l = tid & 63;
    int wr = w >> 1, wc = w & 1;
    int lrow = l & 15, quad = l >> 4;
    int r_in = (l >> 3) & 7, cc = l & 7;
    int ch = cc ^ r_in;                       // swizzled source chunk
    int sw0 = (quad ^ (lrow & 7)) * 8;        // frag-read chunk offset (shorts)
    const short* Ab = T + (size_t)sb * NTOK * DIM;
    f32x4 acc[4][4] = {};
    for (int kk = 0; kk < 8; kk++) {
        if (kk) __syncthreads();
        for (int inst = 0; inst < 4; inst++) {
            int R = w * 32 + inst * 8 + r_in;
            gl2lds(Ab + (size_t)(n0 + R) * 512 + kk * 64 + ch * 8,
                   &As[(w * 32 + inst * 8) * 64]);
            gl2lds(Wt + (size_t)(j0 + R) * 512 + kk * 64 + ch * 8,
                   &Bs[(w * 32 + inst * 8) * 64]);
        }
        __syncthreads();
        for (int c2 = 0; c2 < 2; c2++) {
            int off = c2 ? (sw0 ^ 32) : sw0;
            short8 af[4], bf[4];
            for (int i = 0; i < 4; i++)
                af[i] = *(const short8*)&As[(wr*64 + i*16 + lrow) * 64 + off];
            for (int j = 0; j < 4; j++)
                bf[j] = *(const short8*)&Bs[(wc*64 + j*16 + lrow) * 64 + off];
            for (int i = 0; i < 4; i++)
                for (int j = 0; j < 4; j++)
                    acc[i][j] = __builtin_amdgcn_mfma_f32_16x16x32_bf16(af[i], bf[j], acc[i][j], 0, 0, 0);
        }
    }
    if (j0 >= 512 && j0 < 1024) {
        // ---- V block: transpose tile in LDS (reuse As+Bs as 128x128), write VT ----
        __syncthreads();               // main-loop LDS readers done
        for (int i = 0; i < 4; i++)
            for (int j = 0; j < 4; j++) {
                int jloc = wc * 64 + j * 16 + lrow;           // V row (within tile)
                float bv = bias[j0 + jloc];
                int nloc = wr * 64 + i * 16 + quad * 4;       // n col
                int c8 = nloc >> 3, half = (nloc >> 2) & 1;
                sh4 pk;
                for (int reg = 0; reg < 4; reg++) pk[reg] = f2bf(acc[i][j][reg] + bv);
                *(sh4*)&smem[jloc * 128 + ((c8 ^ (jloc & 15)) * 8) + half * 4] = pk;
            }
        __syncthreads();
        for (int slot = tid; slot < 2048; slot += 256) {
            int row = slot >> 4, seg = slot & 15;
            short8 v = *(const short8*)&smem[row * 128 + ((seg ^ (row & 15)) * 8)];
            *(short8*)(VT + ((size_t)sb * 512 + (j0 - 512) + row) * NTOK + n0 + seg * 8) = v;
        }
    } else {
        for (int i = 0; i < 4; i++)
            for (int j = 0; j < 4; j++) {
                int jj = j0 + wc * 64 + j * 16 + lrow;
                float bv = bias[jj];
                float sc = (jj < 512) ? QSC : 1.0f;   // Q pre-scaled into exp2 domain
                for (int reg = 0; reg < 4; reg++) {
                    int n = n0 + wr * 64 + i * 16 + quad * 4 + reg;
                    QVK[((size_t)sb * NTOK + n) * 1536 + jj] = f2bf((acc[i][j][reg] + bv) * sc);
                }
            }
    }
}

// ---------------- flash attention: R11 per-wave code + XCD-aware block swizzle ----------------
// 1D grid 1152; id%8 = XCD slot held constant per yb so the 36 q-blocks of one
// (branch,b,h) land on one XCD -> K/V working set (590 KB x 4 heads = 2.4 MB)
// stays in that XCD's 4 MiB L2, shortening the DMA drain at each barrier.
__global__ void __launch_bounds__(256)
k_attn(const short* __restrict__ QVK, const short* __restrict__ VT,
       float* __restrict__ out) {
    __shared__ __align__(16) short Ks[64 * 64];
    __shared__ __align__(16) short Vs[64 * 64];
    __shared__ __align__(16) short Qs[64 * 64];   // Q staging; re-used as P (wave-private)
    int id = blockIdx.x;              // 0..1151
    int xcd = id & 7, rem = id >> 3;
    int qt = rem % 36, yhi = rem / 36;
    int yb = yhi * 8 + xcd;           // 0..31
    int br = yb >> 4;
    int b  = (yb >> 3) & 1;
    int h  = yb & 7;
    int tid = threadIdx.x;
    int w = tid >> 6, l = tid & 63;
    int lrow = l & 15, quad = l >> 4;
    int r_in = (l >> 3) & 7, cc = l & 7;
    int ch = cc ^ r_in;
    int sw0 = (quad ^ (lrow & 7)) * 8;
    int n0 = qt * 64;
    const short* Qg = QVK + ((size_t)(br * 2 + b) * NTOK) * 1536 + h * 64;           // exp2-scaled Q
    const short* Kg = QVK + ((size_t)((1 - br) * 2 + b) * NTOK) * 1536 + 1024 + h * 64;
    const short* Vg = VT + ((size_t)(br * 2 + b) * 512 + h * 64) * NTOK;

    // stage Q (wave w: rows w*16..w*16+15)
    for (int inst = 0; inst < 2; inst++) {
        int R = w * 16 + inst * 8 + r_in;
        gl2lds(Qg + (size_t)(n0 + R) * 1536 + ch * 8, &Qs[(w * 16 + inst * 8) * 64]);
    }
    __syncthreads();
    short8 bq0 = *(const short8*)&Qs[(w * 16 + lrow) * 64 + sw0];
    short8 bq1 = *(const short8*)&Qs[(w * 16 + lrow) * 64 + (sw0 ^ 32)];
    short* Pw = &Qs[w * 16 * 64];     // wave-private P region (16 rows)

    short8 ones;
    for (int i = 0; i < 8; i++) ones[i] = (short)0x3F80;   // bf16 1.0

    f32x4 Oacc[4] = {};
    f32x4 lacc = {};

    for (int mt = 0; mt < 36; mt++) {
        int m0 = mt * 64;
        __syncthreads();              // prev-tile readers done (also covers Q->P reuse)
        for (int inst = 0; inst < 2; inst++) {
            int R = w * 16 + inst * 8 + r_in;
            int Rb = (w * 16 + inst * 8) * 64;
            gl2lds(Kg + (size_t)(m0 + R) * 1536 + ch * 8, &Ks[Rb]);
            gl2lds(Vg + (size_t)R * NTOK + m0 + ch * 8, &Vs[Rb]);
        }
        __syncthreads();              // drain DMA

        for (int sub = 0; sub < 4; sub++) {
            short8 ak0 = *(const short8*)&Ks[(sub * 16 + lrow) * 64 + sw0];
            short8 ak1 = *(const short8*)&Ks[(sub * 16 + lrow) * 64 + (sw0 ^ 32)];
            f32x4 a = {};
            a = __builtin_amdgcn_mfma_f32_16x16x32_bf16(ak0, bq0, a, 0, 0, 0);
            a = __builtin_amdgcn_mfma_f32_16x16x32_bf16(ak1, bq1, a, 0, 0, 0);
            float p0 = exp2f(a[0]), p1 = exp2f(a[1]);
            float p2 = exp2f(a[2]), p3 = exp2f(a[3]);
            uint2 pk;
            pk.x = __builtin_amdgcn_perm(fbits(p1), fbits(p0), 0x07060302u);
            pk.y = __builtin_amdgcn_perm(fbits(p3), fbits(p2), 0x07060302u);
            *(uint2*)&Pw[lrow * 64 + (((2 * sub + (quad >> 1)) ^ (lrow & 7)) * 8) + (quad & 1) * 4] = pk;
        }

        // PV + l-sum: same-wave LDS dep only, no barrier
        short8 ap0 = *(const short8*)&Pw[lrow * 64 + sw0];
        short8 ap1 = *(const short8*)&Pw[lrow * 64 + (sw0 ^ 32)];
        lacc = __builtin_amdgcn_mfma_f32_16x16x32_bf16(ones, ap0, lacc, 0, 0, 0);
        lacc = __builtin_amdgcn_mfma_f32_16x16x32_bf16(ones, ap1, lacc, 0, 0, 0);
        for (int ddt = 0; ddt < 4; ddt++) {
            short8 av0 = *(const short8*)&Vs[(ddt * 16 + lrow) * 64 + sw0];
            short8 av1 = *(const short8*)&Vs[(ddt * 16 + lrow) * 64 + (sw0 ^ 32)];
            Oacc[ddt] = __builtin_amdgcn_mfma_f32_16x16x32_bf16(av0, ap0, Oacc[ddt], 0, 0, 0);
            Oacc[ddt] = __builtin_amdgcn_mfma_f32_16x16x32_bf16(av1, ap1, Oacc[ddt], 0, 0, 0);
        }
    }

    float linv = 1.f / lacc[0];       // all rows of lacc identical (ones A-operand)
    int n = n0 + w * 16 + lrow;
    for (int ddt = 0; ddt < 4; ddt++) {
        float4 o;
        o.x = Oacc[ddt][0] * linv;
        o.y = Oacc[ddt][1] * linv;
        o.z = Oacc[ddt][2] * linv;
        o.w = Oacc[ddt][3] * linv;
        if (br == 0)
            *(float4*)&out[((size_t)b * NTOK + n) * 512 + h * 64 + ddt * 16 + quad * 4] = o;
        else
            *(float4*)&out[(size_t)BNC + ((size_t)(h * 2 + b) * NTOK + n) * 64 + ddt * 16 + quad * 4] = o;
    }
}

extern "C" void kernel_launch(void* const* d_in, const int* in_sizes, int n_in,
                              void* d_out, int out_size, void* d_ws, size_t ws_size,
                              hipStream_t stream) {
    const float* x     = (const float*)d_in[0];
    const float* y     = (const float*)d_in[1];
    const float* k_w   = (const float*)d_in[2];
    const float* k_b   = (const float*)d_in[3];
    const float* qv_w  = (const float*)d_in[4];
    const float* qv_b  = (const float*)d_in[5];
    const float* lnx_g = (const float*)d_in[6];
    const float* lnx_b = (const float*)d_in[7];
    const float* lny_g = (const float*)d_in[8];
    const float* lny_b = (const float*)d_in[9];
    float* out = (float*)d_out;

    char* ws = (char*)d_ws;
    float* bias = (float*)ws;                 // 1536 f32 (6144 B, 16B-aligned)
    short* T    = (short*)(ws + 6144);        // 4,718,592 bf16
    short* Wt   = T + 4718592;                // 786,432 bf16
    short* QVK  = Wt + 786432;                // 14,155,776 bf16 (V region unused)
    short* VT   = QVK + 14155776;             // 4,718,592 bf16

    k_pre  <<<1344, 256, 0, stream>>>(x, y, qv_w, k_w, qv_b, k_b,
                                      lnx_g, lnx_b, lny_g, lny_b, T, Wt, bias);
    k_gemm <<<dim3(18, 12, 4), 256, 0, stream>>>(T, Wt, bias, QVK, VT);
    k_attn <<<1152, 256, 0, stream>>>(QVK, VT, out);
}